// Round 1
// baseline (466.973 us; speedup 1.0000x reference)
//
#include <hip/hip_runtime.h>
#include <stdint.h>

// Problem constants
#define NIMG   32
#define CCH    256
#define WDIM   56
#define HW     3136          // 56*56
#define MTOT   (NIMG*HW)     // 100352 = 784 * 128
#define KCTOT  36            // 4 ci-chunks * 9 taps
#define BK     64

typedef __attribute__((ext_vector_type(8))) short    bf16x8;
typedef __attribute__((ext_vector_type(4))) float    f32x4;
typedef __attribute__((ext_vector_type(4))) uint32_t u32x4;

// ---------------- prepass: dequantize weights -> bf16, layout [co][kc][cil] ----------------
// Bw[(co*36 + cc*9 + tap)*64 + cil] = bf16( lut[ widx[co][cc*64+cil][tap] ] )
__global__ __launch_bounds__(256) void dequant_weights(
    const int* __restrict__ widx, const float* __restrict__ lut,
    uint16_t* __restrict__ Bw) {
  int idx = blockIdx.x * 256 + threadIdx.x;        // < 256*36*64 = 589824
  int co  = idx / (KCTOT * BK);
  int r   = idx - co * (KCTOT * BK);
  int kc  = r >> 6;
  int cil = r & 63;
  int cc  = kc / 9;
  int tap = kc - cc * 9;
  int ci  = cc * 64 + cil;
  int wv  = widx[(co * CCH + ci) * 9 + tap];
  uint32_t b  = __float_as_uint(lut[wv]);
  uint32_t rn = (b + 0x7fffu + ((b >> 16) & 1u)) >> 16;   // RN-even to bf16
  Bw[idx] = (uint16_t)rn;
}

// ---------------- main: implicit-GEMM conv via MFMA, halo-A + global-B ----------------
// C[m][co] = sum_{tap,ci} A(m; ci,tap) * W[co][ci][tap]
// A is staged ONCE per 64-channel chunk as a 256-row linear-s halo tile; the 9 taps
// read it at shifted row offsets (masked via a zero row). B fragments come straight
// from L2-resident Bw -> tap loop has NO barriers, 288 MFMAs per barrier interval.
__global__ __launch_bounds__(256, 2) void conv_mfma(
    const float* __restrict__ in, const uint16_t* __restrict__ Bw,
    const float* __restrict__ bias, float* __restrict__ out) {

  // rows 0..255: halo tile, row r holds g = m0 + r - 58 (clamped), 64 bf16 channels.
  // row 256: zeros (masked-out fragment reads land here).
  // Row stride 72 elems (144 B): bank-quad = (r + grp) mod 8 -> conflict-free.
  __shared__ __align__(16) uint16_t A_lds[257 * 72];   // 37.0 KB

  const int t    = threadIdx.x;
  const int lane = t & 63;
  const int wv   = t >> 6;          // wave 0..3
  const int wm   = wv & 1;          // wave m-tile (0..1)
  const int wn   = wv >> 1;         // wave n-tile (0..1)
  const int lrow = lane & 15;
  const int kgrp = lane >> 4;       // 0..3

  const int m0  = blockIdx.x * 128;
  const int co0 = blockIdx.y * 128;

  // zero row init (visible after the first staging barrier)
  if (t < 9) *(u32x4*)((uint8_t*)A_lds + 256 * 144 + t * 16) = (u32x4){0u, 0u, 0u, 0u};

  // staging geometry: 256 threads x 8 iters cover 256 rows x 8 channel-groups
  const int st_r   = t & 31;        // + 32*i -> row
  const int st_grp = t >> 5;        // 0..7 channel-group (8 ch each)

  // per-lane (h,w) of the 4 m-rows this lane's A-fragments cover (for tap masking)
  int hh[4], ww[4];
#pragma unroll
  for (int mi = 0; mi < 4; ++mi) {
    const int m = m0 + wm * 64 + mi * 16 + lrow;
    const int n = m / HW;
    const int s = m - n * HW;
    hh[mi] = s / WDIM;
    ww[mi] = s - hh[mi] * WDIM;
  }

  f32x4 acc[4][4];
#pragma unroll
  for (int i = 0; i < 4; ++i)
#pragma unroll
    for (int j = 0; j < 4; ++j)
      acc[i][j] = (f32x4){0.f, 0.f, 0.f, 0.f};

#pragma unroll 1
  for (int cc = 0; cc < 4; ++cc) {
    if (cc) __syncthreads();   // protect A_lds until all waves finished previous chunk

    // ---- stage A halo: fp32 gather -> bf16 truncate-pack -> ds_write_b128 ----
    // 64 scalar loads/thread per chunk (vs 288 in the per-tap scheme)
#pragma unroll
    for (int i = 0; i < 8; ++i) {
      const int r = st_r + 32 * i;
      long g = (long)m0 + r - 58;
      g = g < 0 ? 0 : (g >= MTOT ? (MTOT - 1) : g);   // clamp; clamped rows are masked at use
      const int n = (int)((unsigned long)g / HW);
      const int s = (int)(g - (long)n * HW);
      const float* p = in + (size_t)n * (CCH * HW) + (size_t)(cc * 64 + st_grp * 8) * HW + s;
      u32x4 pk;
#pragma unroll
      for (int jj = 0; jj < 4; ++jj) {
        const uint32_t b0 = __float_as_uint(p[(size_t)(2 * jj) * HW]);
        const uint32_t b1 = __float_as_uint(p[(size_t)(2 * jj + 1) * HW]);
        pk[jj] = (b0 >> 16) | (b1 & 0xffff0000u);     // truncate-to-bf16 pack
      }
      *(u32x4*)((uint8_t*)A_lds + r * 144 + st_grp * 16) = pk;
    }
    __syncthreads();

    // ---- 9 taps: B frags from global (L2-hot), A frags from LDS, NO barriers ----
#pragma unroll
    for (int tap = 0; tap < 9; ++tap) {
      const int kh = tap / 3;
      const int dh = kh - 1;
      const int dw = (tap - kh * 3) - 1;
      const int d  = dh * WDIM + dw;                  // linear-s shift for this tap
      const int kc = cc * 9 + tap;

      bf16x8 bfb[2][4];
#pragma unroll
      for (int ks = 0; ks < 2; ++ks)
#pragma unroll
        for (int ni = 0; ni < 4; ++ni) {
          const int nrow = wn * 64 + ni * 16 + lrow;
          bfb[ks][ni] = *(const bf16x8*)(
              Bw + ((size_t)(co0 + nrow) * KCTOT + kc) * BK + ks * 32 + kgrp * 8);
        }

#pragma unroll
      for (int mi = 0; mi < 4; ++mi) {
        const bool valid = (((unsigned)(hh[mi] + dh)) < 56u) & (((unsigned)(ww[mi] + dw)) < 56u);
        const int r_real = wm * 64 + mi * 16 + lrow + d + 58;     // in [1, 242]
        const int rbyte  = valid ? r_real * 144 : 256 * 144;      // invalid -> zero row
        const uint8_t* ap = (const uint8_t*)A_lds + rbyte + kgrp * 16;
        const bf16x8 a0 = *(const bf16x8*)ap;          // k = 0..31 slice (this lane's 8)
        const bf16x8 a1 = *(const bf16x8*)(ap + 64);   // k = 32..63 slice
#pragma unroll
        for (int ni = 0; ni < 4; ++ni) {
          acc[mi][ni] = __builtin_amdgcn_mfma_f32_16x16x32_bf16(a0, bfb[0][ni], acc[mi][ni], 0, 0, 0);
          acc[mi][ni] = __builtin_amdgcn_mfma_f32_16x16x32_bf16(a1, bfb[1][ni], acc[mi][ni], 0, 0, 0);
        }
      }
    }
  }

  // ---- epilogue: add bias, store (D: row=(lane>>4)*4+r, col=lane&15) ----
  float bv[4];
#pragma unroll
  for (int ni = 0; ni < 4; ++ni)
    bv[ni] = bias[co0 + wn * 64 + ni * 16 + lrow];

#pragma unroll
  for (int mi = 0; mi < 4; ++mi) {
#pragma unroll
    for (int r = 0; r < 4; ++r) {
      const int mrow = m0 + wm * 64 + mi * 16 + kgrp * 4 + r;
      const int ni_img = mrow / HW;
      const int ss = mrow - ni_img * HW;
      float* ob = out + (size_t)ni_img * (CCH * HW) + ss;
#pragma unroll
      for (int ni = 0; ni < 4; ++ni) {
        const int co = co0 + wn * 64 + ni * 16 + lrow;
        ob[(size_t)co * HW] = acc[mi][ni][r] + bv[ni];
      }
    }
  }
}

extern "C" void kernel_launch(void* const* d_in, const int* in_sizes, int n_in,
                              void* d_out, int out_size, void* d_ws, size_t ws_size,
                              hipStream_t stream) {
  const float* in   = (const float*)d_in[0];
  const int*   widx = (const int*)d_in[1];
  const float* lut  = (const float*)d_in[2];
  const float* bias = (const float*)d_in[3];
  float* out = (float*)d_out;
  uint16_t* Bw = (uint16_t*)d_ws;   // 589824 * 2 B = 1.18 MB scratch

  dequant_weights<<<dim3(589824 / 256), dim3(256), 0, stream>>>(widx, lut, Bw);
  conv_mfma<<<dim3(MTOT / 128, CCH / 128), dim3(256), 0, stream>>>(in, Bw, bias, out);
}